// Round 10
// baseline (249.278 us; speedup 1.0000x reference)
//
#include <hip/hip_runtime.h>
#include <math.h>

#define NH_TOT 524288   // 4096*128
#define N_ATOM 4096
#define N_EDGE 65536

typedef __attribute__((ext_vector_type(8))) short bf16x8;
typedef __attribute__((ext_vector_type(4))) float f32x4;

__device__ __forceinline__ unsigned short f2bf(float f) {
    unsigned u = __builtin_bit_cast(unsigned, f);
    unsigned r = (u + 0x7fffu + ((u >> 16) & 1u)) >> 16;
    return (unsigned short)r;
}
__device__ __forceinline__ float silu(float v) { return v / (1.0f + __expf(-v)); }

// wb layout (bf16 elements):
// ls0@0(32768), ls1@32768(98304), lt0@131072(16384), lt1@147456(16384),
// lt2@163840(16384), dp1@180224(4096), dp2@184320(4096), dp3@188416(4096)
#define WB_LS1 32768
#define WB_LT0 131072
#define WB_LT1 147456
#define WB_LT2 163840
#define WB_DP  180224

// ---------------------------------------------------------------------------
// Setup: [0,64) U1/U2 tables; [64,320) histogram; [320,508) weight bf16 conv
// ---------------------------------------------------------------------------
__global__ __launch_bounds__(256) void k_setup(
    const float* __restrict__ emb_w, const float* __restrict__ emb2_w,
    const int* __restrict__ ei,
    const float* __restrict__ ls0_w, const float* __restrict__ ls1_w,
    const float* __restrict__ lt0_w, const float* __restrict__ lt1_w,
    const float* __restrict__ lt2_w,
    const float* __restrict__ dp1_w, const float* __restrict__ dp2_w,
    const float* __restrict__ dp3_w,
    float* __restrict__ U1, float* __restrict__ U2,
    int* __restrict__ cnt, unsigned short* __restrict__ wb) {
    const int bx = blockIdx.x, tid = threadIdx.x;
    if (bx < 64) {
        __shared__ float se[2][128];
        const int t = bx * 2 + (tid >> 7), h = tid & 127, half = tid >> 7;
        se[half][h] = emb_w[t * 128 + h];
        __syncthreads();
        float u1 = 0.f, u2 = 0.f;
        const float* row = emb2_w + h * 256;
#pragma unroll 8
        for (int k = 0; k < 128; k++) {
            u1 += se[half][k] * row[k];
            u2 += se[half][k] * row[128 + k];
        }
        U1[t * 128 + h] = u1;
        U2[t * 128 + h] = u2;
    } else if (bx < 320) {
        const int e = (bx - 64) * 256 + tid;
        atomicAdd(&cnt[ei[e]], 1);
    } else {
        const int base = (bx - 320) * 1024 + tid * 4;
        const float* src;
        int off;
        if (base < 32768)       { src = ls0_w; off = 0; }
        else if (base < 131072) { src = ls1_w; off = 32768; }
        else if (base < 147456) { src = lt0_w; off = 131072; }
        else if (base < 163840) { src = lt1_w; off = 147456; }
        else if (base < 180224) { src = lt2_w; off = 163840; }
        else if (base < 184320) { src = dp1_w; off = 180224; }
        else if (base < 188416) { src = dp2_w; off = 184320; }
        else                    { src = dp3_w; off = 188416; }
        const float4 v = *(const float4*)(src + (base - off));
        unsigned short* o = wb + base;
        o[0] = f2bf(v.x); o[1] = f2bf(v.y); o[2] = f2bf(v.z); o[3] = f2bf(v.w);
    }
}

__global__ __launch_bounds__(256) void k_scan(const int* __restrict__ cnt, int* __restrict__ off) {
    __shared__ int s[256];
    const int t = threadIdx.x;
    int loc[16];
    int run = 0;
#pragma unroll
    for (int i = 0; i < 16; i++) { run += cnt[t * 16 + i]; loc[i] = run; }
    s[t] = run;
    __syncthreads();
    for (int d = 1; d < 256; d <<= 1) {
        const int add = (t >= d) ? s[t - d] : 0;
        __syncthreads();
        s[t] += add;
        __syncthreads();
    }
    const int base = s[t] - run;
    if (t == 0) off[0] = 0;
#pragma unroll
    for (int i = 0; i < 16; i++) off[t * 16 + i + 1] = base + loc[i];
}

// ---------------------------------------------------------------------------
// k_edge v2: 8 threads per edge (2048 blocks). Group leader does the atomic
// scatter position; broadcast via shfl. Each thread computes 4 rbf values.
// ---------------------------------------------------------------------------
__global__ __launch_bounds__(256) void k_edge(
    const float* __restrict__ edge_vec, const int* __restrict__ ei,
    const int* __restrict__ z, const int* __restrict__ off,
    int* __restrict__ cursor,
    unsigned short* __restrict__ rbf_bf, float4* __restrict__ geom,
    int* __restrict__ u2off) {
    const int idx = blockIdx.x * 256 + threadIdx.x;
    const int e = idx >> 3, s = idx & 7;
    const int lane = threadIdx.x & 63;

    const float evx = edge_vec[3 * e + 0];
    const float evy = edge_vec[3 * e + 1];
    const float evz = edge_vec[3 * e + 2];
    const float d = sqrtf(evx * evx + evy * evy + evz * evz);
    const float cut = (d < 4.5f) ? 0.5f * (__cosf(0.6981317007977318f * d) + 1.0f) : 0.0f;

    int pos = 0;
    if (s == 0) {
        const int src = ei[e];
        pos = off[src] + atomicAdd(&cursor[src], 1);
    }
    pos = __shfl(pos, lane & 56, 64);
    if (s == 0) {
        const float inv = 1.0f / d;
        geom[pos] = make_float4(evx * inv, evy * inv, evz * inv, cut);
        u2off[pos] = z[ei[N_EDGE + e]] << 7;
    }

    const float expd = __expf(-1.1111111111111112f * d);
    const float m0 = 0.011108996538242306f;
    const float dm = (1.0f - m0) * (1.0f / 31.0f);
    const float tb = 0.0625f * (1.0f - m0);
    const float beta = 1.0f / (tb * tb);
    unsigned rb[2];
#pragma unroll
    for (int j = 0; j < 2; j++) {
        const int r = s * 4 + 2 * j;
        const float df0 = expd - (m0 + (float)r * dm);
        const float df1 = expd - (m0 + (float)(r + 1) * dm);
        rb[j] = (unsigned)f2bf(cut * __expf(-beta * df0 * df0)) |
                ((unsigned)f2bf(cut * __expf(-beta * df1 * df1)) << 16);
    }
    *(uint2*)(rbf_bf + (size_t)pos * 32 + s * 4) = make_uint2(rb[0], rb[1]);
}

// ---------------------------------------------------------------------------
// k_node v5 (unchanged from round 9): 8 nodes/block, 512 blocks.
// ---------------------------------------------------------------------------
__global__ __launch_bounds__(256) void k_node(
    const int* __restrict__ z, const int* __restrict__ off,
    const unsigned short* __restrict__ rbf_bf, const float4* __restrict__ geom,
    const int* __restrict__ u2off,
    const float* __restrict__ U1, const float* __restrict__ U2,
    const float* __restrict__ emb2_b,
    const float* __restrict__ dp1_b, const float* __restrict__ dp2_b,
    const float* __restrict__ dp3_b,
    const unsigned short* __restrict__ wb,
    const float* __restrict__ init_g, const float* __restrict__ init_b,
    unsigned short* __restrict__ acc_bf, unsigned short* __restrict__ nrm_bf) {
    const int tid = threadIdx.x;
    const int wave = tid >> 6, lane = tid & 63, lm = lane & 15, lq = lane >> 4;
    const int nb = blockIdx.x * 8;

    const unsigned short* dpw = wb + WB_DP;
    bf16x8 bfr[3][2];
    float bhc[2], bk1[2], bk2[2], bk3[2];
    int cols[2];
#pragma unroll
    for (int t = 0; t < 2; t++) {
        const int col = wave * 32 + t * 16 + lm;
        cols[t] = col;
        bhc[t] = emb2_b[col];
        bk1[t] = dp1_b[col]; bk2[t] = dp2_b[col]; bk3[t] = dp3_b[col];
#pragma unroll
        for (int k = 0; k < 3; k++)
            bfr[k][t] = *(const bf16x8*)(dpw + k * 4096 + col * 32 + lq * 8);
    }

    __shared__ float redS[8][4];
    __shared__ float redQ[8][4];

    float tnA[8], tnB[8];

    for (int nn = 0; nn < 8; nn++) {
        const int n = nb + nn;
        const int beg = off[n];
        const int En = off[n + 1] - beg;
        const int zoff = z[n] << 7;
        const float u1c0 = U1[zoff + cols[0]];
        const float u1c1 = U1[zoff + cols[1]];

        float part[10][2];
#pragma unroll
        for (int p = 0; p < 10; p++) { part[p][0] = 0.f; part[p][1] = 0.f; }

        for (int mi = 0; mi < En; mi += 16) {
            const int arow = beg + min(mi + lm, En - 1);
            const bf16x8 af = *(const bf16x8*)(rbf_bf + (size_t)arow * 32 + lq * 8);
            f32x4 c[3][2];
#pragma unroll
            for (int k = 0; k < 3; k++)
#pragma unroll
                for (int t = 0; t < 2; t++)
                    c[k][t] = __builtin_amdgcn_mfma_f32_16x16x32_bf16(
                        af, bfr[k][t], (f32x4){0.f, 0.f, 0.f, 0.f}, 0, 0, 0);
#pragma unroll
            for (int r = 0; r < 4; r++) {
                const int er = mi + lq * 4 + r;
                const bool valid = er < En;
                const int p = beg + (valid ? er : 0);
                const float4 g = geom[p];
                const int u2o = u2off[p];
#pragma unroll
                for (int t = 0; t < 2; t++) {
                    const float u2v = U2[u2o + cols[t]];
                    const float u1h = (t == 0) ? u1c0 : u1c1;
                    const float cc = valid ? g.w * (u1h + u2v + bhc[t]) : 0.f;
                    const float w1 = (c[0][t][r] + bk1[t]) * cc;
                    const float w2 = (c[1][t][r] + bk2[t]) * cc;
                    const float w3 = (c[2][t][r] + bk3[t]) * cc;
                    part[0][t] += w1;
                    part[1][t] += w2 * g.x; part[2][t] += w2 * g.y; part[3][t] += w2 * g.z;
                    const float tx = w3 * g.x, ty = w3 * g.y;
                    part[4][t] += tx * g.x; part[5][t] += tx * g.y; part[6][t] += tx * g.z;
                    part[7][t] += ty * g.y; part[8][t] += ty * g.z; part[9][t] += w3 * g.z * g.z;
                }
            }
        }

#pragma unroll
        for (int p = 0; p < 10; p++)
#pragma unroll
            for (int t = 0; t < 2; t++) {
                float v = part[p][t];
                v += __shfl_xor(v, 16, 64);
                v += __shfl_xor(v, 32, 64);
                part[p][t] = v;
            }
        if (lq == 0) {
#pragma unroll
            for (int p = 0; p < 10; p++)
#pragma unroll
                for (int t = 0; t < 2; t++)
                    acc_bf[(size_t)p * NH_TOT + n * 128 + cols[t]] = f2bf(part[p][t]);
        }

        float tn[2];
#pragma unroll
        for (int t = 0; t < 2; t++) {
            const float aI = part[0][t];
            const float axv = part[1][t], ayv = part[2][t], azv = part[3][t];
            const float mxx = part[4][t], mxy = part[5][t], mxz = part[6][t];
            const float myy = part[7][t], myz = part[8][t], mzz = part[9][t];
            const float tr3 = (mxx + myy + mzz) * (1.0f / 3.0f);
            const float t00 = aI + mxx - tr3;
            const float t11 = aI + myy - tr3;
            const float t22 = aI + mzz - tr3;
            tn[t] = t00 * t00 + t11 * t11 + t22 * t22 +
                    2.0f * (mxy * mxy + azv * azv + mxz * mxz + ayv * ayv + myz * myz + axv * axv);
        }
        tnA[nn] = tn[0];
        tnB[nn] = tn[1];

        float s = (lq == 0) ? (tn[0] + tn[1]) : 0.f;
        s += __shfl_xor(s, 1, 64);
        s += __shfl_xor(s, 2, 64);
        s += __shfl_xor(s, 4, 64);
        s += __shfl_xor(s, 8, 64);
        if (lane == 0) redS[nn][wave] = s;
    }
    __syncthreads();

    float dvA[8], dvB[8];
#pragma unroll
    for (int nn = 0; nn < 8; nn++) {
        const float mu = (redS[nn][0] + redS[nn][1] + redS[nn][2] + redS[nn][3]) * (1.0f / 128.0f);
        dvA[nn] = tnA[nn] - mu;
        dvB[nn] = tnB[nn] - mu;
        float q = (lq == 0) ? (dvA[nn] * dvA[nn] + dvB[nn] * dvB[nn]) : 0.f;
        q += __shfl_xor(q, 1, 64);
        q += __shfl_xor(q, 2, 64);
        q += __shfl_xor(q, 4, 64);
        q += __shfl_xor(q, 8, 64);
        if (lane == 0) redQ[nn][wave] = q;
    }
    __syncthreads();

    if (lq == 0) {
        const float g0 = init_g[cols[0]], g1 = init_g[cols[1]];
        const float b0 = init_b[cols[0]], b1 = init_b[cols[1]];
#pragma unroll
        for (int nn = 0; nn < 8; nn++) {
            const float var = (redQ[nn][0] + redQ[nn][1] + redQ[nn][2] + redQ[nn][3]) * (1.0f / 128.0f);
            const float rs = rsqrtf(var + 1e-5f);
            const int n = nb + nn;
            nrm_bf[n * 128 + cols[0]] = f2bf(dvA[nn] * rs * g0 + b0);
            nrm_bf[n * 128 + cols[1]] = f2bf(dvB[nn] * rs * g1 + b1);
        }
    }
}

// ---------------------------------------------------------------------------
// Megatail v2: A-operands staged in LDS; B-operand register double-buffer
// prefetch in gates1/gates2/mix; unroll-8 in lin/ol. 512 blocks x 8 nodes.
// ---------------------------------------------------------------------------
__global__ __launch_bounds__(256) void k_megatail(
    const unsigned short* __restrict__ nrm_bf, const unsigned short* __restrict__ acc_bf,
    const unsigned short* __restrict__ wb,
    const float* __restrict__ ls0_b, const float* __restrict__ ls1_b,
    const float* __restrict__ outn_g, const float* __restrict__ outn_b,
    const float* __restrict__ lin_w, const float* __restrict__ lin_b,
    const float* __restrict__ ol1_w, const float* __restrict__ ol1_b,
    const float* __restrict__ ol2_w, const float* __restrict__ ol2_b,
    float* __restrict__ out) {
    const int tid = threadIdx.x, wave = tid >> 6, lane = tid & 63;
    const int lm = lane & 15, lq = lane >> 4;
    const int n0 = blockIdx.x * 8;
    const int ar = (lm < 8) ? lm : 7;

    __shared__ unsigned short accs[10][8][136]; // padded stride: bank-spread
    __shared__ unsigned short nrms[8][136];
    __shared__ unsigned short h1[16][280];
    __shared__ float scal_s[8][388];
    __shared__ float xs[8][392];
    __shared__ float ss[8][132];

    // ---- stage A operands (acc 10x8x128, nrm 8x128) into LDS
#pragma unroll
    for (int j = 0; j < 5; j++) {
        const int i = tid + j * 256;            // 0..1279
        const int row_id = i >> 4, q = i & 15;  // 80 rows x 16 xint4
        const int p = row_id >> 3, r = row_id & 7;
        const uint4 v = *(const uint4*)(acc_bf + (size_t)p * NH_TOT + (size_t)(n0 + r) * 128 + q * 8);
        *(uint4*)(&accs[p][r][q * 8]) = v;
    }
    if (tid < 128) {
        const int r = tid >> 4, q = tid & 15;
        *(uint4*)(&nrms[r][q * 8]) = *(const uint4*)(nrm_bf + (size_t)(n0 + r) * 128 + q * 8);
    }
    __syncthreads();

    // ---- gates GEMM1: h1 = silu(nrm @ ls0^T + b0), B prefetched
    {
        f32x4 acc[4];
#pragma unroll
        for (int j = 0; j < 4; j++) acc[j] = (f32x4){0.f, 0.f, 0.f, 0.f};
        const int cbase = wave * 64;
        bf16x8 bcur[4], bnxt[4];
#pragma unroll
        for (int sn = 0; sn < 4; sn++)
            bcur[sn] = *(const bf16x8*)(wb + (size_t)(cbase + sn * 16 + lm) * 128 + lq * 8);
#pragma unroll
        for (int kc = 0; kc < 128; kc += 32) {
            if (kc < 96) {
#pragma unroll
                for (int sn = 0; sn < 4; sn++)
                    bnxt[sn] = *(const bf16x8*)(wb + (size_t)(cbase + sn * 16 + lm) * 128 + kc + 32 + lq * 8);
            }
            const bf16x8 af = *(const bf16x8*)(&nrms[ar][kc + lq * 8]);
#pragma unroll
            for (int sn = 0; sn < 4; sn++)
                acc[sn] = __builtin_amdgcn_mfma_f32_16x16x32_bf16(af, bcur[sn], acc[sn], 0, 0, 0);
#pragma unroll
            for (int sn = 0; sn < 4; sn++) bcur[sn] = bnxt[sn];
        }
#pragma unroll
        for (int sn = 0; sn < 4; sn++) {
            const int col = cbase + sn * 16 + lm;
            const float bv = ls0_b[col];
#pragma unroll
            for (int r = 0; r < 4; r++)
                h1[lq * 4 + r][col] = f2bf(silu(acc[sn][r] + bv));
        }
    }
    __syncthreads();

    // ---- gates GEMM2: scal = silu(h1 @ ls1^T + b1), B prefetched
    {
        f32x4 acc[6];
#pragma unroll
        for (int j = 0; j < 6; j++) acc[j] = (f32x4){0.f, 0.f, 0.f, 0.f};
        const int cbase = wave * 96;
        const unsigned short* ls1p = wb + WB_LS1;
        bf16x8 bcur[6], bnxt[6];
#pragma unroll
        for (int sn = 0; sn < 6; sn++)
            bcur[sn] = *(const bf16x8*)(ls1p + (size_t)(cbase + sn * 16 + lm) * 256 + lq * 8);
#pragma unroll
        for (int kc = 0; kc < 256; kc += 32) {
            if (kc < 224) {
#pragma unroll
                for (int sn = 0; sn < 6; sn++)
                    bnxt[sn] = *(const bf16x8*)(ls1p + (size_t)(cbase + sn * 16 + lm) * 256 + kc + 32 + lq * 8);
            }
            const bf16x8 af = *(const bf16x8*)(&h1[lm][kc + lq * 8]);
#pragma unroll
            for (int sn = 0; sn < 6; sn++)
                acc[sn] = __builtin_amdgcn_mfma_f32_16x16x32_bf16(af, bcur[sn], acc[sn], 0, 0, 0);
#pragma unroll
            for (int sn = 0; sn < 6; sn++) bcur[sn] = bnxt[sn];
        }
#pragma unroll
        for (int sn = 0; sn < 6; sn++) {
            const int col = cbase + sn * 16 + lm;
            const float bv = ls1_b[col];
#pragma unroll
            for (int r = 0; r < 4; r++) {
                const int node = lq * 4 + r;
                if (node < 8) scal_s[node][col] = silu(acc[sn][r] + bv);
            }
        }
    }
    __syncthreads();

    // ---- mix: flattened 40-iter (plane,kc) loop, A from LDS, B prefetched
    f32x4 e0[2], e1[2], e2[2], trv[2];
#pragma unroll
    for (int sn = 0; sn < 2; sn++) {
        e0[sn] = (f32x4){0.f, 0.f, 0.f, 0.f};
        e1[sn] = (f32x4){0.f, 0.f, 0.f, 0.f};
        e2[sn] = (f32x4){0.f, 0.f, 0.f, 0.f};
        trv[sn] = (f32x4){0.f, 0.f, 0.f, 0.f};
    }
    {
        const int coff = wave * 32;
        f32x4 c0, c1;
        bf16x8 bcur0, bcur1, bnxt0, bnxt1;
        {
            const unsigned short* B = wb + WB_LT0;
            bcur0 = *(const bf16x8*)(B + (size_t)(coff + lm) * 128 + lq * 8);
            bcur1 = *(const bf16x8*)(B + (size_t)(coff + 16 + lm) * 128 + lq * 8);
        }
#pragma unroll
        for (int it = 0; it < 40; it++) {
            const int p = it >> 2, k = it & 3;
            if (it < 39) {
                const int pn = (it + 1) >> 2, kn = (it + 1) & 3;
                const unsigned short* B = wb + (pn == 0 ? WB_LT0 : (pn < 4 ? WB_LT1 : WB_LT2));
                bnxt0 = *(const bf16x8*)(B + (size_t)(coff + lm) * 128 + kn * 32 + lq * 8);
                bnxt1 = *(const bf16x8*)(B + (size_t)(coff + 16 + lm) * 128 + kn * 32 + lq * 8);
            }
            if (k == 0) { c0 = (f32x4){0.f, 0.f, 0.f, 0.f}; c1 = (f32x4){0.f, 0.f, 0.f, 0.f}; }
            const bf16x8 af = *(const bf16x8*)(&accs[p][ar][k * 32 + lq * 8]);
            c0 = __builtin_amdgcn_mfma_f32_16x16x32_bf16(af, bcur0, c0, 0, 0, 0);
            c1 = __builtin_amdgcn_mfma_f32_16x16x32_bf16(af, bcur1, c1, 0, 0, 0);
            bcur0 = bnxt0; bcur1 = bnxt1;
            if (k == 3) {
                if (p == 0)      { e0[0] += c0 * c0; e0[1] += c1 * c1; }
                else if (p < 4)  { e1[0] += c0 * c0; e1[1] += c1 * c1; }
                else if (p == 4 || p == 7 || p == 9) {
                    e2[0] += c0 * c0; e2[1] += c1 * c1;
                    trv[0] += c0;     trv[1] += c1;
                } else {
                    e2[0] += 2.0f * c0 * c0; e2[1] += 2.0f * c1 * c1;
                }
            }
        }
    }

    // ---- combine + gate
    if (lq < 2) {
#pragma unroll
        for (int sn = 0; sn < 2; sn++) {
            const int g = wave * 32 + sn * 16 + lm;
#pragma unroll
            for (int r = 0; r < 4; r++) {
                const int node = lq * 4 + r;
                const float s0 = scal_s[node][3 * g + 0];
                const float s1 = scal_s[node][3 * g + 1];
                const float s2 = scal_s[node][3 * g + 2];
                xs[node][g]       = 3.0f * e0[sn][r] * s0 * s0;
                xs[node][128 + g] = 2.0f * e1[sn][r] * s1 * s1;
                const float tr = trv[sn][r];
                xs[node][256 + g] = (e2[sn][r] - tr * tr * (1.0f / 3.0f)) * s2 * s2;
            }
        }
    }
    __syncthreads();

    // ---- LN(384): wave w normalizes nodes {2w, 2w+1}
#pragma unroll
    for (int i = 0; i < 2; i++) {
        const int node = wave * 2 + i;
        float v[6];
        float s = 0.f;
#pragma unroll
        for (int j = 0; j < 6; j++) { v[j] = xs[node][lane + 64 * j]; s += v[j]; }
#pragma unroll
        for (int o = 1; o < 64; o <<= 1) s += __shfl_xor(s, o, 64);
        const float mu = s * (1.0f / 384.0f);
        float q = 0.f;
#pragma unroll
        for (int j = 0; j < 6; j++) { v[j] -= mu; q += v[j] * v[j]; }
#pragma unroll
        for (int o = 1; o < 64; o <<= 1) q += __shfl_xor(q, o, 64);
        const float rs = rsqrtf(q * (1.0f / 384.0f) + 1e-5f);
#pragma unroll
        for (int j = 0; j < 6; j++) {
            const int col = lane + 64 * j;
            xs[node][col] = v[j] * rs * outn_g[col] + outn_b[col];
        }
    }
    __syncthreads();

    // ---- lin
    {
        const int j = tid & 127, half = tid >> 7;
        float a4[4];
        const float lb = lin_b[j];
#pragma unroll
        for (int i = 0; i < 4; i++) a4[i] = lb;
        const float4* wr = (const float4*)(lin_w + j * 384);
#pragma unroll 8
        for (int k4 = 0; k4 < 96; k4++) {
            const float4 w4 = wr[k4];
#pragma unroll
            for (int i = 0; i < 4; i++) {
                const float4 xv = *(const float4*)&xs[half * 4 + i][k4 * 4];
                a4[i] += w4.x * xv.x + w4.y * xv.y + w4.z * xv.z + w4.w * xv.w;
            }
        }
#pragma unroll
        for (int i = 0; i < 4; i++) ss[half * 4 + i][j] = silu(a4[i]);
    }
    __syncthreads();

    // ---- ol1 + ol2
    {
        const int o = tid & 63, q = tid >> 6;
        float a2v[2];
        const float ob = ol1_b[o];
        a2v[0] = ob; a2v[1] = ob;
        const float4* o4 = (const float4*)(ol1_w + o * 128);
#pragma unroll 8
        for (int k4 = 0; k4 < 32; k4++) {
            const float4 w4 = o4[k4];
#pragma unroll
            for (int i = 0; i < 2; i++) {
                const float4 sv = *(const float4*)&ss[q * 2 + i][k4 * 4];
                a2v[i] += w4.x * sv.x + w4.y * sv.y + w4.z * sv.z + w4.w * sv.w;
            }
        }
        const float w2 = ol2_w[o];
#pragma unroll
        for (int i = 0; i < 2; i++) {
            float v = silu(a2v[i]) * w2;
            for (int s = 32; s > 0; s >>= 1) v += __shfl_down(v, s, 64);
            if (o == 0) out[n0 + q * 2 + i] = v + ol2_b[0];
        }
    }
}

// ---------------------------------------------------------------------------
extern "C" void kernel_launch(void* const* d_in, const int* in_sizes, int n_in,
                              void* d_out, int out_size, void* d_ws, size_t ws_size,
                              hipStream_t stream) {
    (void)in_sizes; (void)n_in; (void)out_size; (void)ws_size;
    const float* edge_vec = (const float*)d_in[0];
    const float* emb_w   = (const float*)d_in[1];
    const float* emb2_w  = (const float*)d_in[2];
    const float* emb2_b  = (const float*)d_in[3];
    const float* dp1_w   = (const float*)d_in[4];
    const float* dp1_b   = (const float*)d_in[5];
    const float* dp2_w   = (const float*)d_in[6];
    const float* dp2_b   = (const float*)d_in[7];
    const float* dp3_w   = (const float*)d_in[8];
    const float* dp3_b   = (const float*)d_in[9];
    const float* lt0_w   = (const float*)d_in[10];
    const float* lt1_w   = (const float*)d_in[11];
    const float* lt2_w   = (const float*)d_in[12];
    const float* ls0_w   = (const float*)d_in[13];
    const float* ls0_b   = (const float*)d_in[14];
    const float* ls1_w   = (const float*)d_in[15];
    const float* ls1_b   = (const float*)d_in[16];
    const float* init_g  = (const float*)d_in[17];
    const float* init_b  = (const float*)d_in[18];
    const float* lin_w   = (const float*)d_in[19];
    const float* lin_b   = (const float*)d_in[20];
    const float* outn_g  = (const float*)d_in[21];
    const float* outn_b  = (const float*)d_in[22];
    const float* ol1_w   = (const float*)d_in[23];
    const float* ol1_b   = (const float*)d_in[24];
    const float* ol2_w   = (const float*)d_in[25];
    const float* ol2_b   = (const float*)d_in[26];
    const int* z  = (const int*)d_in[27];
    const int* ei = (const int*)d_in[28];
    float* out = (float*)d_out;

    char* w = (char*)d_ws;
    int*            cnt    = (int*)(w);                      // -> 16384
    int*            cursor = (int*)(w + 16384);              // -> 32768
    int*            off    = (int*)(w + 32768);              // -> 49408
    unsigned short* wb     = (unsigned short*)(w + 49408);   // -> 434432
    float*          U1     = (float*)(w + 434432);           // -> 499968
    float*          U2     = (float*)(w + 499968);           // -> 565504
    int*            u2off  = (int*)(w + 565504);             // -> 827648
    float4*         geom   = (float4*)(w + 827648);          // -> 1876224
    unsigned short* rbf_bf = (unsigned short*)(w + 1876224); // -> 6070528
    unsigned short* nrm_bf = (unsigned short*)(w + 6070528); // -> 7119104
    unsigned short* acc_bf = (unsigned short*)(w + 7119104); // -> 17604864

    hipMemsetAsync(w, 0, 32768, stream);  // cnt + cursor
    k_setup<<<dim3(508), dim3(256), 0, stream>>>(emb_w, emb2_w, ei,
                                                 ls0_w, ls1_w, lt0_w, lt1_w, lt2_w,
                                                 dp1_w, dp2_w, dp3_w,
                                                 U1, U2, cnt, wb);
    k_scan<<<dim3(1), dim3(256), 0, stream>>>(cnt, off);
    k_edge<<<dim3(2048), dim3(256), 0, stream>>>(edge_vec, ei, z, off, cursor,
                                                 rbf_bf, geom, u2off);
    k_node<<<dim3(512), dim3(256), 0, stream>>>(z, off, rbf_bf, geom, u2off, U1, U2,
                                                emb2_b, dp1_b, dp2_b, dp3_b, wb,
                                                init_g, init_b, acc_bf, nrm_bf);
    k_megatail<<<dim3(512), dim3(256), 0, stream>>>(nrm_bf, acc_bf, wb, ls0_b, ls1_b,
                                                    outn_g, outn_b, lin_w, lin_b,
                                                    ol1_w, ol1_b, ol2_w, ol2_b, out);
}

// Round 11
// 237.678 us; speedup vs baseline: 1.0488x; 1.0488x over previous
//
#include <hip/hip_runtime.h>
#include <math.h>

#define NH_TOT 524288   // 4096*128
#define N_ATOM 4096
#define N_EDGE 65536

typedef __attribute__((ext_vector_type(8))) short bf16x8;
typedef __attribute__((ext_vector_type(4))) float f32x4;

__device__ __forceinline__ unsigned short f2bf(float f) {
    unsigned u = __builtin_bit_cast(unsigned, f);
    unsigned r = (u + 0x7fffu + ((u >> 16) & 1u)) >> 16;
    return (unsigned short)r;
}
__device__ __forceinline__ float silu(float v) { return v / (1.0f + __expf(-v)); }

// wb layout (bf16 elements):
// ls0@0(32768), ls1@32768(98304), lt0@131072(16384), lt1@147456(16384),
// lt2@163840(16384), dp1@180224(4096), dp2@184320(4096), dp3@188416(4096)
#define WB_LS1 32768
#define WB_LT0 131072
#define WB_LT1 147456
#define WB_LT2 163840
#define WB_DP  180224

// ---------------------------------------------------------------------------
// Setup: [0,4096) U1/U2 one wave per (type,h), coalesced; [4096,4352) hist;
// [4352,4540) weight bf16 conversion.
// ---------------------------------------------------------------------------
__global__ __launch_bounds__(256) void k_setup(
    const float* __restrict__ emb_w, const float* __restrict__ emb2_w,
    const int* __restrict__ ei,
    const float* __restrict__ ls0_w, const float* __restrict__ ls1_w,
    const float* __restrict__ lt0_w, const float* __restrict__ lt1_w,
    const float* __restrict__ lt2_w,
    const float* __restrict__ dp1_w, const float* __restrict__ dp2_w,
    const float* __restrict__ dp3_w,
    float* __restrict__ U1, float* __restrict__ U2,
    int* __restrict__ cnt, unsigned short* __restrict__ wb) {
    const int bx = blockIdx.x, tid = threadIdx.x;
    if (bx < 4096) {
        const int idx = bx * 4 + (tid >> 6);
        const int t = idx >> 7, h = idx & 127;
        const int lane = tid & 63;
        const float e0 = emb_w[t * 128 + lane];
        const float e1 = emb_w[t * 128 + 64 + lane];
        const float* row = emb2_w + h * 256;
        const float w0 = row[lane], w1 = row[64 + lane];
        const float w2 = row[128 + lane], w3 = row[192 + lane];
        float u1 = e0 * w0 + e1 * w1;
        float u2 = e0 * w2 + e1 * w3;
#pragma unroll
        for (int o = 1; o < 64; o <<= 1) {
            u1 += __shfl_xor(u1, o, 64);
            u2 += __shfl_xor(u2, o, 64);
        }
        if (lane == 0) {
            U1[t * 128 + h] = u1;
            U2[t * 128 + h] = u2;
        }
    } else if (bx < 4352) {
        const int e = (bx - 4096) * 256 + tid;
        atomicAdd(&cnt[ei[e]], 1);
    } else {
        const int base = (bx - 4352) * 1024 + tid * 4;
        const float* src;
        int off;
        if (base < 32768)       { src = ls0_w; off = 0; }
        else if (base < 131072) { src = ls1_w; off = 32768; }
        else if (base < 147456) { src = lt0_w; off = 131072; }
        else if (base < 163840) { src = lt1_w; off = 147456; }
        else if (base < 180224) { src = lt2_w; off = 163840; }
        else if (base < 184320) { src = dp1_w; off = 180224; }
        else if (base < 188416) { src = dp2_w; off = 184320; }
        else                    { src = dp3_w; off = 188416; }
        const float4 v = *(const float4*)(src + (base - off));
        unsigned short* o = wb + base;
        o[0] = f2bf(v.x); o[1] = f2bf(v.y); o[2] = f2bf(v.z); o[3] = f2bf(v.w);
    }
}

__global__ __launch_bounds__(256) void k_scan(const int* __restrict__ cnt, int* __restrict__ off) {
    __shared__ int s[256];
    const int t = threadIdx.x;
    int loc[16];
    int run = 0;
#pragma unroll
    for (int i = 0; i < 16; i++) { run += cnt[t * 16 + i]; loc[i] = run; }
    s[t] = run;
    __syncthreads();
    for (int d = 1; d < 256; d <<= 1) {
        const int add = (t >= d) ? s[t - d] : 0;
        __syncthreads();
        s[t] += add;
        __syncthreads();
    }
    const int base = s[t] - run;
    if (t == 0) off[0] = 0;
#pragma unroll
    for (int i = 0; i < 16; i++) off[t * 16 + i + 1] = base + loc[i];
}

__global__ __launch_bounds__(256) void k_scatter(const int* __restrict__ ei,
                                                 const int* __restrict__ off,
                                                 int* __restrict__ cursor,
                                                 int* __restrict__ order) {
    const int e = blockIdx.x * 256 + threadIdx.x;
    const int s = ei[e];
    order[off[s] + atomicAdd(&cursor[s], 1)] = e;
}

// ---------------------------------------------------------------------------
// k_node v6: rbf/geom computed IN-KERNEL from edge_vec (k_edge eliminated).
// 4 nodes/block, 1024 blocks, 256 threads. Wave w owns cols w*32..w*32+31.
// Per tile: lane lm computes its edge row's d/cut/rbf (8 exp) -> A-fragment;
// epilogue gets geometry via shfl from the owning lane.
// ---------------------------------------------------------------------------
__global__ __launch_bounds__(256) void k_node(
    const int* __restrict__ z, const int* __restrict__ off,
    const int* __restrict__ order, const int* __restrict__ ei,
    const float* __restrict__ edge_vec,
    const float* __restrict__ U1, const float* __restrict__ U2,
    const float* __restrict__ emb2_b,
    const float* __restrict__ dp1_b, const float* __restrict__ dp2_b,
    const float* __restrict__ dp3_b,
    const unsigned short* __restrict__ wb,
    const float* __restrict__ init_g, const float* __restrict__ init_b,
    unsigned short* __restrict__ acc_bf, unsigned short* __restrict__ nrm_bf) {
    const int tid = threadIdx.x;
    const int wave = tid >> 6, lane = tid & 63, lm = lane & 15, lq = lane >> 4;
    const int nb = blockIdx.x * 4;

    const unsigned short* dpw = wb + WB_DP;
    bf16x8 bfr[3][2];
    float bhc[2], bk1[2], bk2[2], bk3[2];
    int cols[2];
#pragma unroll
    for (int t = 0; t < 2; t++) {
        const int col = wave * 32 + t * 16 + lm;
        cols[t] = col;
        bhc[t] = emb2_b[col];
        bk1[t] = dp1_b[col]; bk2[t] = dp2_b[col]; bk3[t] = dp3_b[col];
#pragma unroll
        for (int k = 0; k < 3; k++)
            bfr[k][t] = *(const bf16x8*)(dpw + k * 4096 + col * 32 + lq * 8);
    }

    const float m0 = 0.011108996538242306f;
    const float dm = (1.0f - m0) * (1.0f / 31.0f);
    const float tb = 0.0625f * (1.0f - m0);
    const float beta = 1.0f / (tb * tb);
    const float mean0 = m0 + (float)(lq * 8) * dm;   // lane's first k mean

    __shared__ float redS[4][4];
    __shared__ float redQ[4][4];

    float tnA[4], tnB[4];

    for (int nn = 0; nn < 4; nn++) {
        const int n = nb + nn;
        const int beg = off[n];
        const int En = off[n + 1] - beg;
        const int zoff = z[n] << 7;
        const float u1c0 = U1[zoff + cols[0]];
        const float u1c1 = U1[zoff + cols[1]];

        float part[10][2];
#pragma unroll
        for (int p = 0; p < 10; p++) { part[p][0] = 0.f; part[p][1] = 0.f; }

        for (int mi = 0; mi < En; mi += 16) {
            const int e = order[beg + min(mi + lm, En - 1)];
            const float evx = edge_vec[3 * e + 0];
            const float evy = edge_vec[3 * e + 1];
            const float evz = edge_vec[3 * e + 2];
            const float d = sqrtf(evx * evx + evy * evy + evz * evz);
            const float inv = 1.0f / d;
            const float cut = (d < 4.5f) ? 0.5f * (__cosf(0.6981317007977318f * d) + 1.0f) : 0.0f;
            const float vx = evx * inv, vy = evy * inv, vz = evz * inv;
            const int u2o = z[ei[N_EDGE + e]] << 7;
            const float expd = __expf(-1.1111111111111112f * d);

            union { bf16x8 v; unsigned short s[8]; } uf;
#pragma unroll
            for (int j = 0; j < 8; j++) {
                const float df = expd - (mean0 + (float)j * dm);
                uf.s[j] = f2bf(cut * __expf(-beta * df * df));
            }
            const bf16x8 af = uf.v;

            f32x4 c[3][2];
#pragma unroll
            for (int k = 0; k < 3; k++)
#pragma unroll
                for (int t = 0; t < 2; t++)
                    c[k][t] = __builtin_amdgcn_mfma_f32_16x16x32_bf16(
                        af, bfr[k][t], (f32x4){0.f, 0.f, 0.f, 0.f}, 0, 0, 0);

#pragma unroll
            for (int r = 0; r < 4; r++) {
                const int er = mi + lq * 4 + r;
                const bool valid = er < En;
                const int sl = (lane & 48) | (lq * 4 + r);   // source lane owning row
                const float gvx = __shfl(vx, sl, 64);
                const float gvy = __shfl(vy, sl, 64);
                const float gvz = __shfl(vz, sl, 64);
                const float gct = __shfl(cut, sl, 64);
                const int   go  = __shfl(u2o, sl, 64);
#pragma unroll
                for (int t = 0; t < 2; t++) {
                    const float u2v = U2[go + cols[t]];
                    const float u1h = (t == 0) ? u1c0 : u1c1;
                    const float cc = valid ? gct * (u1h + u2v + bhc[t]) : 0.f;
                    const float w1 = (c[0][t][r] + bk1[t]) * cc;
                    const float w2 = (c[1][t][r] + bk2[t]) * cc;
                    const float w3 = (c[2][t][r] + bk3[t]) * cc;
                    part[0][t] += w1;
                    part[1][t] += w2 * gvx; part[2][t] += w2 * gvy; part[3][t] += w2 * gvz;
                    const float tx = w3 * gvx, ty = w3 * gvy;
                    part[4][t] += tx * gvx; part[5][t] += tx * gvy; part[6][t] += tx * gvz;
                    part[7][t] += ty * gvy; part[8][t] += ty * gvz; part[9][t] += w3 * gvz * gvz;
                }
            }
        }

#pragma unroll
        for (int p = 0; p < 10; p++)
#pragma unroll
            for (int t = 0; t < 2; t++) {
                float v = part[p][t];
                v += __shfl_xor(v, 16, 64);
                v += __shfl_xor(v, 32, 64);
                part[p][t] = v;
            }
        if (lq == 0) {
#pragma unroll
            for (int p = 0; p < 10; p++)
#pragma unroll
                for (int t = 0; t < 2; t++)
                    acc_bf[(size_t)p * NH_TOT + n * 128 + cols[t]] = f2bf(part[p][t]);
        }

        float tn[2];
#pragma unroll
        for (int t = 0; t < 2; t++) {
            const float aI = part[0][t];
            const float axv = part[1][t], ayv = part[2][t], azv = part[3][t];
            const float mxx = part[4][t], mxy = part[5][t], mxz = part[6][t];
            const float myy = part[7][t], myz = part[8][t], mzz = part[9][t];
            const float tr3 = (mxx + myy + mzz) * (1.0f / 3.0f);
            const float t00 = aI + mxx - tr3;
            const float t11 = aI + myy - tr3;
            const float t22 = aI + mzz - tr3;
            tn[t] = t00 * t00 + t11 * t11 + t22 * t22 +
                    2.0f * (mxy * mxy + azv * azv + mxz * mxz + ayv * ayv + myz * myz + axv * axv);
        }
        tnA[nn] = tn[0];
        tnB[nn] = tn[1];

        float s = (lq == 0) ? (tn[0] + tn[1]) : 0.f;
        s += __shfl_xor(s, 1, 64);
        s += __shfl_xor(s, 2, 64);
        s += __shfl_xor(s, 4, 64);
        s += __shfl_xor(s, 8, 64);
        if (lane == 0) redS[nn][wave] = s;
    }
    __syncthreads();

    float dvA[4], dvB[4];
#pragma unroll
    for (int nn = 0; nn < 4; nn++) {
        const float mu = (redS[nn][0] + redS[nn][1] + redS[nn][2] + redS[nn][3]) * (1.0f / 128.0f);
        dvA[nn] = tnA[nn] - mu;
        dvB[nn] = tnB[nn] - mu;
        float q = (lq == 0) ? (dvA[nn] * dvA[nn] + dvB[nn] * dvB[nn]) : 0.f;
        q += __shfl_xor(q, 1, 64);
        q += __shfl_xor(q, 2, 64);
        q += __shfl_xor(q, 4, 64);
        q += __shfl_xor(q, 8, 64);
        if (lane == 0) redQ[nn][wave] = q;
    }
    __syncthreads();

    if (lq == 0) {
        const float g0 = init_g[cols[0]], g1 = init_g[cols[1]];
        const float b0 = init_b[cols[0]], b1 = init_b[cols[1]];
#pragma unroll
        for (int nn = 0; nn < 4; nn++) {
            const float var = (redQ[nn][0] + redQ[nn][1] + redQ[nn][2] + redQ[nn][3]) * (1.0f / 128.0f);
            const float rs = rsqrtf(var + 1e-5f);
            const int n = nb + nn;
            nrm_bf[n * 128 + cols[0]] = f2bf(dvA[nn] * rs * g0 + b0);
            nrm_bf[n * 128 + cols[1]] = f2bf(dvB[nn] * rs * g1 + b1);
        }
    }
}

// ---------------------------------------------------------------------------
// Megatail (round-9 exact): gates + 10-plane mix + combine + LN(384) + lin
// + ol1 + ol2. Block = 8 nodes, 256 thr, 512 blocks.
// ---------------------------------------------------------------------------
__global__ __launch_bounds__(256) void k_megatail(
    const unsigned short* __restrict__ nrm_bf, const unsigned short* __restrict__ acc_bf,
    const unsigned short* __restrict__ wb,
    const float* __restrict__ ls0_b, const float* __restrict__ ls1_b,
    const float* __restrict__ outn_g, const float* __restrict__ outn_b,
    const float* __restrict__ lin_w, const float* __restrict__ lin_b,
    const float* __restrict__ ol1_w, const float* __restrict__ ol1_b,
    const float* __restrict__ ol2_w, const float* __restrict__ ol2_b,
    float* __restrict__ out) {
    const int tid = threadIdx.x, wave = tid >> 6, lane = tid & 63;
    const int lm = lane & 15, lq = lane >> 4;
    const int n0 = blockIdx.x * 8;

    __shared__ unsigned short h1[16][280];
    __shared__ float scal_s[8][388];
    __shared__ float xs[8][392];
    __shared__ float ss[8][132];

    // ---- gates GEMM1
    {
        f32x4 acc[4];
#pragma unroll
        for (int j = 0; j < 4; j++) acc[j] = (f32x4){0.f, 0.f, 0.f, 0.f};
        const int cbase = wave * 64;
#pragma unroll
        for (int kc = 0; kc < 128; kc += 32) {
            const int arow = n0 + min(lm, 7);
            const bf16x8 af = *(const bf16x8*)(nrm_bf + (size_t)arow * 128 + kc + lq * 8);
#pragma unroll
            for (int sn = 0; sn < 4; sn++) {
                const bf16x8 b = *(const bf16x8*)(wb + (size_t)(cbase + sn * 16 + lm) * 128 + kc + lq * 8);
                acc[sn] = __builtin_amdgcn_mfma_f32_16x16x32_bf16(af, b, acc[sn], 0, 0, 0);
            }
        }
#pragma unroll
        for (int sn = 0; sn < 4; sn++) {
            const int col = cbase + sn * 16 + lm;
            const float bv = ls0_b[col];
#pragma unroll
            for (int r = 0; r < 4; r++)
                h1[lq * 4 + r][col] = f2bf(silu(acc[sn][r] + bv));
        }
    }
    __syncthreads();
    // ---- gates GEMM2
    {
        f32x4 acc[6];
#pragma unroll
        for (int j = 0; j < 6; j++) acc[j] = (f32x4){0.f, 0.f, 0.f, 0.f};
        const int cbase = wave * 96;
        const unsigned short* ls1p = wb + WB_LS1;
#pragma unroll 2
        for (int kc = 0; kc < 256; kc += 32) {
            const bf16x8 af = *(const bf16x8*)(&h1[lm][kc + lq * 8]);
#pragma unroll
            for (int sn = 0; sn < 6; sn++) {
                const bf16x8 b = *(const bf16x8*)(ls1p + (size_t)(cbase + sn * 16 + lm) * 256 + kc + lq * 8);
                acc[sn] = __builtin_amdgcn_mfma_f32_16x16x32_bf16(af, b, acc[sn], 0, 0, 0);
            }
        }
#pragma unroll
        for (int sn = 0; sn < 6; sn++) {
            const int col = cbase + sn * 16 + lm;
            const float bv = ls1_b[col];
#pragma unroll
            for (int r = 0; r < 4; r++) {
                const int node = lq * 4 + r;
                if (node < 8) scal_s[node][col] = silu(acc[sn][r] + bv);
            }
        }
    }
    __syncthreads();

    // ---- mix: 10 plane GEMMs
    f32x4 e0[2], e1[2], e2[2], trv[2];
#pragma unroll
    for (int sn = 0; sn < 2; sn++) {
        e0[sn] = (f32x4){0.f, 0.f, 0.f, 0.f};
        e1[sn] = (f32x4){0.f, 0.f, 0.f, 0.f};
        e2[sn] = (f32x4){0.f, 0.f, 0.f, 0.f};
        trv[sn] = (f32x4){0.f, 0.f, 0.f, 0.f};
    }
#pragma unroll
    for (int p = 0; p < 10; p++) {
        const unsigned short* A = acc_bf + (size_t)p * NH_TOT;
        const unsigned short* B = wb + (p == 0 ? WB_LT0 : (p < 4 ? WB_LT1 : WB_LT2));
        f32x4 c[2];
        c[0] = (f32x4){0.f, 0.f, 0.f, 0.f};
        c[1] = (f32x4){0.f, 0.f, 0.f, 0.f};
#pragma unroll
        for (int kc = 0; kc < 128; kc += 32) {
            const int arow = n0 + min(lm, 7);
            const bf16x8 af = *(const bf16x8*)(A + (size_t)arow * 128 + kc + lq * 8);
#pragma unroll
            for (int sn = 0; sn < 2; sn++) {
                const bf16x8 b = *(const bf16x8*)(B + (size_t)(wave * 32 + sn * 16 + lm) * 128 + kc + lq * 8);
                c[sn] = __builtin_amdgcn_mfma_f32_16x16x32_bf16(af, b, c[sn], 0, 0, 0);
            }
        }
#pragma unroll
        for (int sn = 0; sn < 2; sn++) {
            if (p == 0)      e0[sn] += c[sn] * c[sn];
            else if (p < 4)  e1[sn] += c[sn] * c[sn];
            else if (p == 4 || p == 7 || p == 9) { e2[sn] += c[sn] * c[sn]; trv[sn] += c[sn]; }
            else             e2[sn] += 2.0f * c[sn] * c[sn];
        }
    }

    // ---- combine + gate
    if (lq < 2) {
#pragma unroll
        for (int sn = 0; sn < 2; sn++) {
            const int g = wave * 32 + sn * 16 + lm;
#pragma unroll
            for (int r = 0; r < 4; r++) {
                const int node = lq * 4 + r;
                const float s0 = scal_s[node][3 * g + 0];
                const float s1 = scal_s[node][3 * g + 1];
                const float s2 = scal_s[node][3 * g + 2];
                xs[node][g]       = 3.0f * e0[sn][r] * s0 * s0;
                xs[node][128 + g] = 2.0f * e1[sn][r] * s1 * s1;
                const float tr = trv[sn][r];
                xs[node][256 + g] = (e2[sn][r] - tr * tr * (1.0f / 3.0f)) * s2 * s2;
            }
        }
    }
    __syncthreads();

    // ---- LN(384): wave w normalizes nodes {2w, 2w+1}
#pragma unroll
    for (int i = 0; i < 2; i++) {
        const int node = wave * 2 + i;
        float v[6];
        float s = 0.f;
#pragma unroll
        for (int j = 0; j < 6; j++) { v[j] = xs[node][lane + 64 * j]; s += v[j]; }
#pragma unroll
        for (int o = 1; o < 64; o <<= 1) s += __shfl_xor(s, o, 64);
        const float mu = s * (1.0f / 384.0f);
        float q = 0.f;
#pragma unroll
        for (int j = 0; j < 6; j++) { v[j] -= mu; q += v[j] * v[j]; }
#pragma unroll
        for (int o = 1; o < 64; o <<= 1) q += __shfl_xor(q, o, 64);
        const float rs = rsqrtf(q * (1.0f / 384.0f) + 1e-5f);
#pragma unroll
        for (int j = 0; j < 6; j++) {
            const int col = lane + 64 * j;
            xs[node][col] = v[j] * rs * outn_g[col] + outn_b[col];
        }
    }
    __syncthreads();

    // ---- lin
    {
        const int j = tid & 127, half = tid >> 7;
        float a4[4];
        const float lb = lin_b[j];
#pragma unroll
        for (int i = 0; i < 4; i++) a4[i] = lb;
        const float4* wr = (const float4*)(lin_w + j * 384);
#pragma unroll 2
        for (int k4 = 0; k4 < 96; k4++) {
            const float4 w4 = wr[k4];
#pragma unroll
            for (int i = 0; i < 4; i++) {
                const float4 xv = *(const float4*)&xs[half * 4 + i][k4 * 4];
                a4[i] += w4.x * xv.x + w4.y * xv.y + w4.z * xv.z + w4.w * xv.w;
            }
        }
#pragma unroll
        for (int i = 0; i < 4; i++) ss[half * 4 + i][j] = silu(a4[i]);
    }
    __syncthreads();

    // ---- ol1 + ol2
    {
        const int o = tid & 63, q = tid >> 6;
        float a2v[2];
        const float ob = ol1_b[o];
        a2v[0] = ob; a2v[1] = ob;
        const float4* o4 = (const float4*)(ol1_w + o * 128);
#pragma unroll 4
        for (int k4 = 0; k4 < 32; k4++) {
            const float4 w4 = o4[k4];
#pragma unroll
            for (int i = 0; i < 2; i++) {
                const float4 sv = *(const float4*)&ss[q * 2 + i][k4 * 4];
                a2v[i] += w4.x * sv.x + w4.y * sv.y + w4.z * sv.z + w4.w * sv.w;
            }
        }
        const float w2 = ol2_w[o];
#pragma unroll
        for (int i = 0; i < 2; i++) {
            float v = silu(a2v[i]) * w2;
            for (int s = 32; s > 0; s >>= 1) v += __shfl_down(v, s, 64);
            if (o == 0) out[n0 + q * 2 + i] = v + ol2_b[0];
        }
    }
}

// ---------------------------------------------------------------------------
extern "C" void kernel_launch(void* const* d_in, const int* in_sizes, int n_in,
                              void* d_out, int out_size, void* d_ws, size_t ws_size,
                              hipStream_t stream) {
    (void)in_sizes; (void)n_in; (void)out_size; (void)ws_size;
    const float* edge_vec = (const float*)d_in[0];
    const float* emb_w   = (const float*)d_in[1];
    const float* emb2_w  = (const float*)d_in[2];
    const float* emb2_b  = (const float*)d_in[3];
    const float* dp1_w   = (const float*)d_in[4];
    const float* dp1_b   = (const float*)d_in[5];
    const float* dp2_w   = (const float*)d_in[6];
    const float* dp2_b   = (const float*)d_in[7];
    const float* dp3_w   = (const float*)d_in[8];
    const float* dp3_b   = (const float*)d_in[9];
    const float* lt0_w   = (const float*)d_in[10];
    const float* lt1_w   = (const float*)d_in[11];
    const float* lt2_w   = (const float*)d_in[12];
    const float* ls0_w   = (const float*)d_in[13];
    const float* ls0_b   = (const float*)d_in[14];
    const float* ls1_w   = (const float*)d_in[15];
    const float* ls1_b   = (const float*)d_in[16];
    const float* init_g  = (const float*)d_in[17];
    const float* init_b  = (const float*)d_in[18];
    const float* lin_w   = (const float*)d_in[19];
    const float* lin_b   = (const float*)d_in[20];
    const float* outn_g  = (const float*)d_in[21];
    const float* outn_b  = (const float*)d_in[22];
    const float* ol1_w   = (const float*)d_in[23];
    const float* ol1_b   = (const float*)d_in[24];
    const float* ol2_w   = (const float*)d_in[25];
    const float* ol2_b   = (const float*)d_in[26];
    const int* z  = (const int*)d_in[27];
    const int* ei = (const int*)d_in[28];
    float* out = (float*)d_out;

    char* w = (char*)d_ws;
    int*            cnt    = (int*)(w);                      // -> 16384
    int*            cursor = (int*)(w + 16384);              // -> 32768
    int*            off    = (int*)(w + 32768);              // -> 49408
    unsigned short* wb     = (unsigned short*)(w + 49408);   // -> 434432
    float*          U1     = (float*)(w + 434432);           // -> 499968
    float*          U2     = (float*)(w + 499968);           // -> 565504
    int*            order  = (int*)(w + 565504);             // -> 827648
    unsigned short* nrm_bf = (unsigned short*)(w + 827648);  // -> 1876224
    unsigned short* acc_bf = (unsigned short*)(w + 1876224); // -> 12361984

    hipMemsetAsync(w, 0, 32768, stream);  // cnt + cursor
    k_setup<<<dim3(4540), dim3(256), 0, stream>>>(emb_w, emb2_w, ei,
                                                  ls0_w, ls1_w, lt0_w, lt1_w, lt2_w,
                                                  dp1_w, dp2_w, dp3_w,
                                                  U1, U2, cnt, wb);
    k_scan<<<dim3(1), dim3(256), 0, stream>>>(cnt, off);
    k_scatter<<<dim3(256), dim3(256), 0, stream>>>(ei, off, cursor, order);
    k_node<<<dim3(1024), dim3(256), 0, stream>>>(z, off, order, ei, edge_vec, U1, U2,
                                                 emb2_b, dp1_b, dp2_b, dp3_b, wb,
                                                 init_g, init_b, acc_bf, nrm_bf);
    k_megatail<<<dim3(512), dim3(256), 0, stream>>>(nrm_bf, acc_bf, wb, ls0_b, ls1_b,
                                                    outn_g, outn_b, lin_w, lin_b,
                                                    ol1_w, ol1_b, ol2_w, ol2_b, out);
}

// Round 12
// 213.315 us; speedup vs baseline: 1.1686x; 1.1142x over previous
//
#include <hip/hip_runtime.h>
#include <math.h>

#define NH_TOT 524288   // 4096*128
#define N_ATOM 4096
#define N_EDGE 65536

typedef __attribute__((ext_vector_type(8))) short bf16x8;
typedef __attribute__((ext_vector_type(4))) float f32x4;

__device__ __forceinline__ unsigned short f2bf(float f) {
    unsigned u = __builtin_bit_cast(unsigned, f);
    unsigned r = (u + 0x7fffu + ((u >> 16) & 1u)) >> 16;
    return (unsigned short)r;
}
__device__ __forceinline__ float silu(float v) { return v / (1.0f + __expf(-v)); }

// wb layout (bf16 elements):
// ls0@0(32768), ls1@32768(98304), lt0@131072(16384), lt1@147456(16384),
// lt2@163840(16384), dp1@180224(4096), dp2@184320(4096), dp3@188416(4096)
#define WB_LS1 32768
#define WB_LT0 131072
#define WB_LT1 147456
#define WB_LT2 163840
#define WB_DP  180224

// ---------------------------------------------------------------------------
// Setup: [0,4096) U1/U2 (one wave per (t,h), coalesced); [4096,4352) edge
// scatter into padded per-node buckets (no scan!); [4352,4540) weight conv.
// ---------------------------------------------------------------------------
__global__ __launch_bounds__(256) void k_setup(
    const float* __restrict__ emb_w, const float* __restrict__ emb2_w,
    const int* __restrict__ ei,
    const float* __restrict__ ls0_w, const float* __restrict__ ls1_w,
    const float* __restrict__ lt0_w, const float* __restrict__ lt1_w,
    const float* __restrict__ lt2_w,
    const float* __restrict__ dp1_w, const float* __restrict__ dp2_w,
    const float* __restrict__ dp3_w,
    float* __restrict__ U1, float* __restrict__ U2,
    int* __restrict__ cursor, int* __restrict__ order_pad,
    unsigned short* __restrict__ wb) {
    const int bx = blockIdx.x, tid = threadIdx.x;
    if (bx < 4096) {
        const int idx = bx * 4 + (tid >> 6);
        const int t = idx >> 7, h = idx & 127;
        const int lane = tid & 63;
        const float e0 = emb_w[t * 128 + lane];
        const float e1 = emb_w[t * 128 + 64 + lane];
        const float* row = emb2_w + h * 256;
        const float w0 = row[lane], w1 = row[64 + lane];
        const float w2 = row[128 + lane], w3 = row[192 + lane];
        float u1 = e0 * w0 + e1 * w1;
        float u2 = e0 * w2 + e1 * w3;
#pragma unroll
        for (int o = 1; o < 64; o <<= 1) {
            u1 += __shfl_xor(u1, o, 64);
            u2 += __shfl_xor(u2, o, 64);
        }
        if (lane == 0) {
            U1[t * 128 + h] = u1;
            U2[t * 128 + h] = u2;
        }
    } else if (bx < 4352) {
        const int e = (bx - 4096) * 256 + tid;
        const int src = ei[e];
        const int pos = atomicAdd(&cursor[src], 1);
        if (pos < 64) order_pad[(src << 6) + pos] = e;
    } else {
        const int base = (bx - 4352) * 1024 + tid * 4;
        const float* src;
        int off;
        if (base < 32768)       { src = ls0_w; off = 0; }
        else if (base < 131072) { src = ls1_w; off = 32768; }
        else if (base < 147456) { src = lt0_w; off = 131072; }
        else if (base < 163840) { src = lt1_w; off = 147456; }
        else if (base < 180224) { src = lt2_w; off = 163840; }
        else if (base < 184320) { src = dp1_w; off = 180224; }
        else if (base < 188416) { src = dp2_w; off = 184320; }
        else                    { src = dp3_w; off = 188416; }
        const float4 v = *(const float4*)(src + (base - off));
        unsigned short* o = wb + base;
        o[0] = f2bf(v.x); o[1] = f2bf(v.y); o[2] = f2bf(v.z); o[3] = f2bf(v.w);
    }
}

// ---------------------------------------------------------------------------
// k_fused: edge accumulation (MFMA, in-kernel rbf) + tensor_norm + LN(init)
// + gates + 10-plane mix + combine + LN(384) + lin + ol1 + ol2.
// Block = 8 nodes, 256 threads, 512 blocks. acc/nrm live in LDS only.
// ---------------------------------------------------------------------------
__global__ __launch_bounds__(256) void k_fused(
    const int* __restrict__ z, const int* __restrict__ ecnt,
    const int* __restrict__ order_pad, const int* __restrict__ ei,
    const float* __restrict__ edge_vec,
    const float* __restrict__ U1, const float* __restrict__ U2,
    const float* __restrict__ emb2_b,
    const float* __restrict__ dp1_b, const float* __restrict__ dp2_b,
    const float* __restrict__ dp3_b,
    const unsigned short* __restrict__ wb,
    const float* __restrict__ init_g, const float* __restrict__ init_b,
    const float* __restrict__ ls0_b, const float* __restrict__ ls1_b,
    const float* __restrict__ outn_g, const float* __restrict__ outn_b,
    const float* __restrict__ lin_w, const float* __restrict__ lin_b,
    const float* __restrict__ ol1_w, const float* __restrict__ ol1_b,
    const float* __restrict__ ol2_w, const float* __restrict__ ol2_b,
    float* __restrict__ out) {
    const int tid = threadIdx.x;
    const int wave = tid >> 6, lane = tid & 63, lm = lane & 15, lq = lane >> 4;
    const int n0 = blockIdx.x * 8;
    const int ar = (lm < 8) ? lm : 7;

    __shared__ alignas(16) unsigned short accs[10][8][136];
    __shared__ alignas(16) unsigned short nrms[8][136];
    __shared__ unsigned short h1[16][280];
    __shared__ float scal_s[8][388];
    __shared__ float ss[8][132];
    __shared__ float redS[8][4];
    __shared__ float redQ[8][4];
    float (*xs)[392] = reinterpret_cast<float(*)[392]>(&accs[0][0][0]);  // alias (accs dead after mix)

    // ======================= EDGE PHASE =======================
    const unsigned short* dpw = wb + WB_DP;
    bf16x8 bfr[3][2];
    float bhc[2], bk1[2], bk2[2], bk3[2];
    int cols[2];
#pragma unroll
    for (int t = 0; t < 2; t++) {
        const int col = wave * 32 + t * 16 + lm;
        cols[t] = col;
        bhc[t] = emb2_b[col];
        bk1[t] = dp1_b[col]; bk2[t] = dp2_b[col]; bk3[t] = dp3_b[col];
#pragma unroll
        for (int k = 0; k < 3; k++)
            bfr[k][t] = *(const bf16x8*)(dpw + k * 4096 + col * 32 + lq * 8);
    }

    const float m0 = 0.011108996538242306f;
    const float dm = (1.0f - m0) * (1.0f / 31.0f);
    const float tb = 0.0625f * (1.0f - m0);
    const float beta = 1.0f / (tb * tb);
    const float mean0 = m0 + (float)(lq * 8) * dm;

    float tnA[8], tnB[8];

    for (int nn = 0; nn < 8; nn++) {
        const int n = n0 + nn;
        const int En = min(ecnt[n], 64);
        const int beg = n << 6;
        const int zoff = z[n] << 7;
        const float u1c0 = U1[zoff + cols[0]];
        const float u1c1 = U1[zoff + cols[1]];

        float part[10][2];
#pragma unroll
        for (int p = 0; p < 10; p++) { part[p][0] = 0.f; part[p][1] = 0.f; }

        for (int mi = 0; mi < En; mi += 16) {
            const int e = order_pad[beg + min(mi + lm, En - 1)];
            const float evx = edge_vec[3 * e + 0];
            const float evy = edge_vec[3 * e + 1];
            const float evz = edge_vec[3 * e + 2];
            const float d = sqrtf(evx * evx + evy * evy + evz * evz);
            const float inv = 1.0f / d;
            const float cut = (d < 4.5f) ? 0.5f * (__cosf(0.6981317007977318f * d) + 1.0f) : 0.0f;
            const float vx = evx * inv, vy = evy * inv, vz = evz * inv;
            const int u2o = z[ei[N_EDGE + e]] << 7;
            const float expd = __expf(-1.1111111111111112f * d);

            union { bf16x8 v; unsigned short s[8]; } uf;
#pragma unroll
            for (int j = 0; j < 8; j++) {
                const float df = expd - (mean0 + (float)j * dm);
                uf.s[j] = f2bf(cut * __expf(-beta * df * df));
            }
            const bf16x8 af = uf.v;

            f32x4 c[3][2];
#pragma unroll
            for (int k = 0; k < 3; k++)
#pragma unroll
                for (int t = 0; t < 2; t++)
                    c[k][t] = __builtin_amdgcn_mfma_f32_16x16x32_bf16(
                        af, bfr[k][t], (f32x4){0.f, 0.f, 0.f, 0.f}, 0, 0, 0);

#pragma unroll
            for (int r = 0; r < 4; r++) {
                const int er = mi + lq * 4 + r;
                const bool valid = er < En;
                const int sl = (lane & 48) | (lq * 4 + r);
                const float gvx = __shfl(vx, sl, 64);
                const float gvy = __shfl(vy, sl, 64);
                const float gvz = __shfl(vz, sl, 64);
                const float gct = __shfl(cut, sl, 64);
                const int   go  = __shfl(u2o, sl, 64);
#pragma unroll
                for (int t = 0; t < 2; t++) {
                    const float u2v = U2[go + cols[t]];
                    const float u1h = (t == 0) ? u1c0 : u1c1;
                    const float cc = valid ? gct * (u1h + u2v + bhc[t]) : 0.f;
                    const float w1 = (c[0][t][r] + bk1[t]) * cc;
                    const float w2 = (c[1][t][r] + bk2[t]) * cc;
                    const float w3 = (c[2][t][r] + bk3[t]) * cc;
                    part[0][t] += w1;
                    part[1][t] += w2 * gvx; part[2][t] += w2 * gvy; part[3][t] += w2 * gvz;
                    const float tx = w3 * gvx, ty = w3 * gvy;
                    part[4][t] += tx * gvx; part[5][t] += tx * gvy; part[6][t] += tx * gvz;
                    part[7][t] += ty * gvy; part[8][t] += ty * gvz; part[9][t] += w3 * gvz * gvz;
                }
            }
        }

#pragma unroll
        for (int p = 0; p < 10; p++)
#pragma unroll
            for (int t = 0; t < 2; t++) {
                float v = part[p][t];
                v += __shfl_xor(v, 16, 64);
                v += __shfl_xor(v, 32, 64);
                part[p][t] = v;
            }
        if (lq == 0) {
#pragma unroll
            for (int p = 0; p < 10; p++)
#pragma unroll
                for (int t = 0; t < 2; t++)
                    accs[p][nn][cols[t]] = f2bf(part[p][t]);
        }

        float tn[2];
#pragma unroll
        for (int t = 0; t < 2; t++) {
            const float aI = part[0][t];
            const float axv = part[1][t], ayv = part[2][t], azv = part[3][t];
            const float mxx = part[4][t], mxy = part[5][t], mxz = part[6][t];
            const float myy = part[7][t], myz = part[8][t], mzz = part[9][t];
            const float tr3 = (mxx + myy + mzz) * (1.0f / 3.0f);
            const float t00 = aI + mxx - tr3;
            const float t11 = aI + myy - tr3;
            const float t22 = aI + mzz - tr3;
            tn[t] = t00 * t00 + t11 * t11 + t22 * t22 +
                    2.0f * (mxy * mxy + azv * azv + mxz * mxz + ayv * ayv + myz * myz + axv * axv);
        }
        tnA[nn] = tn[0];
        tnB[nn] = tn[1];

        float s = (lq == 0) ? (tn[0] + tn[1]) : 0.f;
        s += __shfl_xor(s, 1, 64);
        s += __shfl_xor(s, 2, 64);
        s += __shfl_xor(s, 4, 64);
        s += __shfl_xor(s, 8, 64);
        if (lane == 0) redS[nn][wave] = s;
    }
    __syncthreads();

    {
        float dvA[8], dvB[8];
#pragma unroll
        for (int nn = 0; nn < 8; nn++) {
            const float mu = (redS[nn][0] + redS[nn][1] + redS[nn][2] + redS[nn][3]) * (1.0f / 128.0f);
            dvA[nn] = tnA[nn] - mu;
            dvB[nn] = tnB[nn] - mu;
            float q = (lq == 0) ? (dvA[nn] * dvA[nn] + dvB[nn] * dvB[nn]) : 0.f;
            q += __shfl_xor(q, 1, 64);
            q += __shfl_xor(q, 2, 64);
            q += __shfl_xor(q, 4, 64);
            q += __shfl_xor(q, 8, 64);
            if (lane == 0) redQ[nn][wave] = q;
        }
        __syncthreads();
        if (lq == 0) {
            const float g0 = init_g[cols[0]], g1 = init_g[cols[1]];
            const float b0 = init_b[cols[0]], b1 = init_b[cols[1]];
#pragma unroll
            for (int nn = 0; nn < 8; nn++) {
                const float var = (redQ[nn][0] + redQ[nn][1] + redQ[nn][2] + redQ[nn][3]) * (1.0f / 128.0f);
                const float rs = rsqrtf(var + 1e-5f);
                nrms[nn][cols[0]] = f2bf(dvA[nn] * rs * g0 + b0);
                nrms[nn][cols[1]] = f2bf(dvB[nn] * rs * g1 + b1);
            }
        }
    }
    __syncthreads();

    // ======================= TAIL PHASE (round-9 structure) =======================
    // ---- gates GEMM1
    {
        f32x4 acc[4];
#pragma unroll
        for (int j = 0; j < 4; j++) acc[j] = (f32x4){0.f, 0.f, 0.f, 0.f};
        const int cbase = wave * 64;
#pragma unroll
        for (int kc = 0; kc < 128; kc += 32) {
            const bf16x8 af = *(const bf16x8*)(&nrms[ar][kc + lq * 8]);
#pragma unroll
            for (int sn = 0; sn < 4; sn++) {
                const bf16x8 b = *(const bf16x8*)(wb + (size_t)(cbase + sn * 16 + lm) * 128 + kc + lq * 8);
                acc[sn] = __builtin_amdgcn_mfma_f32_16x16x32_bf16(af, b, acc[sn], 0, 0, 0);
            }
        }
#pragma unroll
        for (int sn = 0; sn < 4; sn++) {
            const int col = cbase + sn * 16 + lm;
            const float bv = ls0_b[col];
#pragma unroll
            for (int r = 0; r < 4; r++)
                h1[lq * 4 + r][col] = f2bf(silu(acc[sn][r] + bv));
        }
    }
    __syncthreads();
    // ---- gates GEMM2
    {
        f32x4 acc[6];
#pragma unroll
        for (int j = 0; j < 6; j++) acc[j] = (f32x4){0.f, 0.f, 0.f, 0.f};
        const int cbase = wave * 96;
        const unsigned short* ls1p = wb + WB_LS1;
#pragma unroll 2
        for (int kc = 0; kc < 256; kc += 32) {
            const bf16x8 af = *(const bf16x8*)(&h1[lm][kc + lq * 8]);
#pragma unroll
            for (int sn = 0; sn < 6; sn++) {
                const bf16x8 b = *(const bf16x8*)(ls1p + (size_t)(cbase + sn * 16 + lm) * 256 + kc + lq * 8);
                acc[sn] = __builtin_amdgcn_mfma_f32_16x16x32_bf16(af, b, acc[sn], 0, 0, 0);
            }
        }
#pragma unroll
        for (int sn = 0; sn < 6; sn++) {
            const int col = cbase + sn * 16 + lm;
            const float bv = ls1_b[col];
#pragma unroll
            for (int r = 0; r < 4; r++) {
                const int node = lq * 4 + r;
                if (node < 8) scal_s[node][col] = silu(acc[sn][r] + bv);
            }
        }
    }
    __syncthreads();

    // ---- mix: 10 plane GEMMs, A from LDS accs
    f32x4 e0[2], e1[2], e2[2], trv[2];
#pragma unroll
    for (int sn = 0; sn < 2; sn++) {
        e0[sn] = (f32x4){0.f, 0.f, 0.f, 0.f};
        e1[sn] = (f32x4){0.f, 0.f, 0.f, 0.f};
        e2[sn] = (f32x4){0.f, 0.f, 0.f, 0.f};
        trv[sn] = (f32x4){0.f, 0.f, 0.f, 0.f};
    }
#pragma unroll
    for (int p = 0; p < 10; p++) {
        const unsigned short* B = wb + (p == 0 ? WB_LT0 : (p < 4 ? WB_LT1 : WB_LT2));
        f32x4 c[2];
        c[0] = (f32x4){0.f, 0.f, 0.f, 0.f};
        c[1] = (f32x4){0.f, 0.f, 0.f, 0.f};
#pragma unroll
        for (int kc = 0; kc < 128; kc += 32) {
            const bf16x8 af = *(const bf16x8*)(&accs[p][ar][kc + lq * 8]);
#pragma unroll
            for (int sn = 0; sn < 2; sn++) {
                const bf16x8 b = *(const bf16x8*)(B + (size_t)(wave * 32 + sn * 16 + lm) * 128 + kc + lq * 8);
                c[sn] = __builtin_amdgcn_mfma_f32_16x16x32_bf16(af, b, c[sn], 0, 0, 0);
            }
        }
#pragma unroll
        for (int sn = 0; sn < 2; sn++) {
            if (p == 0)      e0[sn] += c[sn] * c[sn];
            else if (p < 4)  e1[sn] += c[sn] * c[sn];
            else if (p == 4 || p == 7 || p == 9) { e2[sn] += c[sn] * c[sn]; trv[sn] += c[sn]; }
            else             e2[sn] += 2.0f * c[sn] * c[sn];
        }
    }
    __syncthreads();   // accs dead -> xs alias becomes writable

    // ---- combine + gate
    if (lq < 2) {
#pragma unroll
        for (int sn = 0; sn < 2; sn++) {
            const int g = wave * 32 + sn * 16 + lm;
#pragma unroll
            for (int r = 0; r < 4; r++) {
                const int node = lq * 4 + r;
                const float s0 = scal_s[node][3 * g + 0];
                const float s1 = scal_s[node][3 * g + 1];
                const float s2 = scal_s[node][3 * g + 2];
                xs[node][g]       = 3.0f * e0[sn][r] * s0 * s0;
                xs[node][128 + g] = 2.0f * e1[sn][r] * s1 * s1;
                const float tr = trv[sn][r];
                xs[node][256 + g] = (e2[sn][r] - tr * tr * (1.0f / 3.0f)) * s2 * s2;
            }
        }
    }
    __syncthreads();

    // ---- LN(384): wave w normalizes nodes {2w, 2w+1}
#pragma unroll
    for (int i = 0; i < 2; i++) {
        const int node = wave * 2 + i;
        float v[6];
        float s = 0.f;
#pragma unroll
        for (int j = 0; j < 6; j++) { v[j] = xs[node][lane + 64 * j]; s += v[j]; }
#pragma unroll
        for (int o = 1; o < 64; o <<= 1) s += __shfl_xor(s, o, 64);
        const float mu = s * (1.0f / 384.0f);
        float q = 0.f;
#pragma unroll
        for (int j = 0; j < 6; j++) { v[j] -= mu; q += v[j] * v[j]; }
#pragma unroll
        for (int o = 1; o < 64; o <<= 1) q += __shfl_xor(q, o, 64);
        const float rs = rsqrtf(q * (1.0f / 384.0f) + 1e-5f);
#pragma unroll
        for (int j = 0; j < 6; j++) {
            const int col = lane + 64 * j;
            xs[node][col] = v[j] * rs * outn_g[col] + outn_b[col];
        }
    }
    __syncthreads();

    // ---- lin
    {
        const int j = tid & 127, half = tid >> 7;
        float a4[4];
        const float lb = lin_b[j];
#pragma unroll
        for (int i = 0; i < 4; i++) a4[i] = lb;
        const float4* wr = (const float4*)(lin_w + j * 384);
#pragma unroll 2
        for (int k4 = 0; k4 < 96; k4++) {
            const float4 w4 = wr[k4];
#pragma unroll
            for (int i = 0; i < 4; i++) {
                const float4 xv = *(const float4*)&xs[half * 4 + i][k4 * 4];
                a4[i] += w4.x * xv.x + w4.y * xv.y + w4.z * xv.z + w4.w * xv.w;
            }
        }
#pragma unroll
        for (int i = 0; i < 4; i++) ss[half * 4 + i][j] = silu(a4[i]);
    }
    __syncthreads();

    // ---- ol1 + ol2
    {
        const int o = tid & 63, q = tid >> 6;
        float a2v[2];
        const float ob = ol1_b[o];
        a2v[0] = ob; a2v[1] = ob;
        const float4* o4 = (const float4*)(ol1_w + o * 128);
#pragma unroll 4
        for (int k4 = 0; k4 < 32; k4++) {
            const float4 w4 = o4[k4];
#pragma unroll
            for (int i = 0; i < 2; i++) {
                const float4 sv = *(const float4*)&ss[q * 2 + i][k4 * 4];
                a2v[i] += w4.x * sv.x + w4.y * sv.y + w4.z * sv.z + w4.w * sv.w;
            }
        }
        const float w2 = ol2_w[o];
#pragma unroll
        for (int i = 0; i < 2; i++) {
            float v = silu(a2v[i]) * w2;
            for (int s = 32; s > 0; s >>= 1) v += __shfl_down(v, s, 64);
            if (o == 0) out[n0 + q * 2 + i] = v + ol2_b[0];
        }
    }
}

// ---------------------------------------------------------------------------
extern "C" void kernel_launch(void* const* d_in, const int* in_sizes, int n_in,
                              void* d_out, int out_size, void* d_ws, size_t ws_size,
                              hipStream_t stream) {
    (void)in_sizes; (void)n_in; (void)out_size; (void)ws_size;
    const float* edge_vec = (const float*)d_in[0];
    const float* emb_w   = (const float*)d_in[1];
    const float* emb2_w  = (const float*)d_in[2];
    const float* emb2_b  = (const float*)d_in[3];
    const float* dp1_w   = (const float*)d_in[4];
    const float* dp1_b   = (const float*)d_in[5];
    const float* dp2_w   = (const float*)d_in[6];
    const float* dp2_b   = (const float*)d_in[7];
    const float* dp3_w   = (const float*)d_in[8];
    const float* dp3_b   = (const float*)d_in[9];
    const float* lt0_w   = (const float*)d_in[10];
    const float* lt1_w   = (const float*)d_in[11];
    const float* lt2_w   = (const float*)d_in[12];
    const float* ls0_w   = (const float*)d_in[13];
    const float* ls0_b   = (const float*)d_in[14];
    const float* ls1_w   = (const float*)d_in[15];
    const float* ls1_b   = (const float*)d_in[16];
    const float* init_g  = (const float*)d_in[17];
    const float* init_b  = (const float*)d_in[18];
    const float* lin_w   = (const float*)d_in[19];
    const float* lin_b   = (const float*)d_in[20];
    const float* outn_g  = (const float*)d_in[21];
    const float* outn_b  = (const float*)d_in[22];
    const float* ol1_w   = (const float*)d_in[23];
    const float* ol1_b   = (const float*)d_in[24];
    const float* ol2_w   = (const float*)d_in[25];
    const float* ol2_b   = (const float*)d_in[26];
    const int* z  = (const int*)d_in[27];
    const int* ei = (const int*)d_in[28];
    float* out = (float*)d_out;

    char* w = (char*)d_ws;
    int*            cursor    = (int*)(w);                      // -> 16384
    unsigned short* wb        = (unsigned short*)(w + 16384);   // 385024 B -> 401408
    float*          U1        = (float*)(w + 401408);           // -> 466944
    float*          U2        = (float*)(w + 466944);           // -> 532480
    int*            order_pad = (int*)(w + 532480);             // 1 MB -> 1581056

    hipMemsetAsync(w, 0, 16384, stream);  // cursor
    k_setup<<<dim3(4540), dim3(256), 0, stream>>>(emb_w, emb2_w, ei,
                                                  ls0_w, ls1_w, lt0_w, lt1_w, lt2_w,
                                                  dp1_w, dp2_w, dp3_w,
                                                  U1, U2, cursor, order_pad, wb);
    k_fused<<<dim3(512), dim3(256), 0, stream>>>(z, cursor, order_pad, ei, edge_vec,
                                                 U1, U2, emb2_b, dp1_b, dp2_b, dp3_b, wb,
                                                 init_g, init_b, ls0_b, ls1_b,
                                                 outn_g, outn_b, lin_w, lin_b,
                                                 ol1_w, ol1_b, ol2_w, ol2_b, out);
}